// Round 1
// 230.079 us; speedup vs baseline: 1.0139x; 1.0139x over previous
//
#include <hip/hip_runtime.h>

#define D 64
#define LOG2E 1.4426950408889634f

using frag_ab = __attribute__((ext_vector_type(8))) short;  // 8 bf16 (4 VGPRs)
using f32x4   = __attribute__((ext_vector_type(4))) float;  // 4 fp32 acc

__device__ __forceinline__ unsigned short f2bf(float f) {      // RNE fp32->bf16
    unsigned int bits = __float_as_uint(f);
    return (unsigned short)((bits + 0x7fffu + ((bits >> 16) & 1u)) >> 16);
}

__device__ __forceinline__ frag_ab pack8(float4 a, float4 b) { // 8 fp32 -> bf16x8 frag
    frag_ab f;
    f[0] = (short)f2bf(a.x); f[1] = (short)f2bf(a.y);
    f[2] = (short)f2bf(a.z); f[3] = (short)f2bf(a.w);
    f[4] = (short)f2bf(b.x); f[5] = (short)f2bf(b.y);
    f[6] = (short)f2bf(b.z); f[7] = (short)f2bf(b.w);
    return f;
}

// z = x @ W^T + b via MFMA bf16 (z is stored bf16 anyway, so bf16 inputs are free)
// + FUSED degree count. Atomics issued first so their latency hides under the GEMM.
// Per wave: 16x64 output tile = 2 K-steps x 4 col-tiles = 8x mfma_f32_16x16x32_bf16.
// A-frags from LDS (stride-68 pad: conflict-free b128); B-frags straight from W
// (16 KB, L1-resident; B^T == W so each lane's 8 k-elems are contiguous).
// zxb[row*64+c] = uint{ bf16(z_c) | bf16(x_c)<<16 }.
__global__ __launch_bounds__(256) void gemm_z_count(const float* __restrict__ x,
                                                    const float* __restrict__ W,
                                                    const float* __restrict__ b,
                                                    unsigned int* __restrict__ zxb,
                                                    int n,
                                                    const int* __restrict__ dst,
                                                    int* __restrict__ deg,
                                                    int* __restrict__ slot,
                                                    int e_cnt) {
    __shared__ float xs[64 * 68];   // 64 rows x stride 68 (17.4 KB; +4 pad keeps 16B align, 2-way alias only)
    int tid = threadIdx.x;

    // ---- fused count: issue early so atomic latency hides under GEMM ----
    int gtid = blockIdx.x * 256 + tid;
    int nthreads = gridDim.x * 256;
    int e0 = -1, e1 = -1, e2 = -1, s0 = 0, s1 = 0, s2 = 0;
    {
        int ee = gtid;
        if (ee < e_cnt) { e0 = ee; s0 = atomicAdd(&deg[dst[ee]], 1); ee += nthreads; }
        if (ee < e_cnt) { e1 = ee; s1 = atomicAdd(&deg[dst[ee]], 1); ee += nthreads; }
        if (ee < e_cnt) { e2 = ee; s2 = atomicAdd(&deg[dst[ee]], 1); }
    }

    // ---- stage x tile (fp32, also reused for the bf16(x) pack in the epilogue) ----
    int row0 = blockIdx.x * 64;
    for (int i = tid; i < 64 * 16; i += 256) {
        int r = i >> 4;
        int gr = row0 + r;
        float4 v = (gr < n) ? ((const float4*)x)[(size_t)gr * 16 + (i & 15)]
                            : make_float4(0.f, 0.f, 0.f, 0.f);
        *(float4*)&xs[r * 68 + (i & 15) * 4] = v;
    }

    int l  = tid & 63;    // lane
    int w  = tid >> 6;    // wave 0..3 -> rows w*16..w*16+15
    int lr = l & 15;      // A-row / B-col / D-col within 16-tile
    int hi = l >> 4;      // 0..3
    int lk = hi * 8;      // k offset within K=32 chunk

    // ---- B frags from global W (z = x@W^T  =>  B^T == W, rows contiguous) ----
    frag_ab bfr[4][2];
#pragma unroll
    for (int colt = 0; colt < 4; ++colt) {
#pragma unroll
        for (int ks = 0; ks < 2; ++ks) {
            const float* wp = W + (colt * 16 + lr) * 64 + ks * 32 + lk;
            bfr[colt][ks] = pack8(*(const float4*)wp, *(const float4*)(wp + 4));
        }
    }

    __syncthreads();

    // ---- A frags from LDS (2x ds_read_b128 per frag, conflict-free at stride 68) ----
    frag_ab afr[2];
#pragma unroll
    for (int ks = 0; ks < 2; ++ks) {
        const float* ap = &xs[(w * 16 + lr) * 68 + ks * 32 + lk];
        afr[ks] = pack8(*(const float4*)ap, *(const float4*)(ap + 4));
    }

    f32x4 zero = {0.f, 0.f, 0.f, 0.f};
    f32x4 acc[4] = {zero, zero, zero, zero};
#pragma unroll
    for (int ks = 0; ks < 2; ++ks) {
#pragma unroll
        for (int colt = 0; colt < 4; ++colt) {
            acc[colt] = __builtin_amdgcn_mfma_f32_16x16x32_bf16(
                afr[ks], bfr[colt][ks], acc[colt], 0, 0, 0);
        }
    }

    // ---- epilogue: D mapping col=lane&15, row=(lane>>4)*4+reg (m89-verified) ----
#pragma unroll
    for (int colt = 0; colt < 4; ++colt) {
        int col = colt * 16 + lr;
        float bb = b[col];
#pragma unroll
        for (int r = 0; r < 4; ++r) {
            int lrow = w * 16 + hi * 4 + r;
            int row  = row0 + lrow;
            if (row < n) {
                float z  = acc[colt][r] + bb;
                float xv = xs[lrow * 68 + col];
                unsigned int u = (unsigned int)f2bf(z) |
                                 ((unsigned int)f2bf(xv) << 16);
                zxb[(size_t)row * 64 + col] = u;   // 64B-segment coalesced
            }
        }
    }

    // ---- write captured slots (independent of GEMM result) ----
    if (e0 >= 0) slot[e0] = s0;
    if (e1 >= 0) slot[e1] = s1;
    if (e2 >= 0) slot[e2] = s2;
}

// ---- 3-phase coalesced scan ----
__global__ __launch_bounds__(256) void scan_part(const int* __restrict__ deg,
                                                 int* __restrict__ part, int n) {
    __shared__ int red[256];
    int t = threadIdx.x;
    int i = blockIdx.x * 256 + t;
    red[t] = (i < n) ? deg[i] : 0;
    __syncthreads();
    for (int off = 128; off >= 1; off >>= 1) {
        if (t < off) red[t] += red[t + off];
        __syncthreads();
    }
    if (t == 0) part[blockIdx.x] = red[0];
}

__global__ __launch_bounds__(512) void scan_top(int* __restrict__ part, int B) {
    __shared__ int s[512];
    int t = threadIdx.x;
    int v = (t < B) ? part[t] : 0;
    s[t] = v;
    __syncthreads();
    for (int off = 1; off < 512; off <<= 1) {
        int u = (t >= off) ? s[t - off] : 0;
        __syncthreads();
        s[t] += u;
        __syncthreads();
    }
    if (t < B) part[t] = s[t] - v;   // exclusive
}

__global__ __launch_bounds__(256) void scan_final(const int* __restrict__ deg,
                                                  const int* __restrict__ part,
                                                  int* __restrict__ rowstart, int n) {
    __shared__ int s[256];
    int t = threadIdx.x;
    int i = blockIdx.x * 256 + t;
    int v = (i < n) ? deg[i] : 0;
    s[t] = v;
    __syncthreads();
    for (int off = 1; off < 256; off <<= 1) {
        int u = (t >= off) ? s[t - off] : 0;
        __syncthreads();
        s[t] += u;
        __syncthreads();
    }
    int incl = s[t] + part[blockIdx.x];
    if (i < n) rowstart[i] = incl - v;
    if (i == n - 1) rowstart[n] = incl;
}

__global__ __launch_bounds__(256) void csr_fill_slot(const int* __restrict__ src,
                                                     const int* __restrict__ dst,
                                                     const int* __restrict__ rowstart,
                                                     const int* __restrict__ slot,
                                                     int* __restrict__ srcids, int e_cnt) {
    int e = blockIdx.x * 256 + threadIdx.x;
    if (e >= e_cnt) return;
    srcids[rowstart[dst[e]] + slot[e]] = src[e];
}

// wave-per-node, quarter-wave per edge, 8 edges/iter (2x unroll).
// bf16-packed row: zxb[row*64 + d] = { bf16 z_d | bf16 x_d << 16 }, 256 B/row.
__global__ __launch_bounds__(256) void gather4b(const int* __restrict__ srcids,
                                                const int* __restrict__ rowstart,
                                                const unsigned int* __restrict__ zxb,
                                                const float* __restrict__ att,
                                                float* __restrict__ out, int n) {
    int lane = threadIdx.x & 63;
    int node = blockIdx.x * 4 + (threadIdx.x >> 6);
    if (node >= n) return;
    int q = lane & 15;                 // dim group: 4q..4q+3
    int h = lane >> 4;                 // edge slot 0..3
    int rs = rowstart[node], re = rowstart[node + 1];

    const uint4 zdv = *(const uint4*)(zxb + (size_t)node * 64 + 4 * q);
    float zd0 = __uint_as_float(zdv.x << 16);
    float zd1 = __uint_as_float(zdv.y << 16);
    float zd2 = __uint_as_float(zdv.z << 16);
    float zd3 = __uint_as_float(zdv.w << 16);
    float4 av = *(const float4*)(att + 4 * q);
    float a0 = av.x * LOG2E, a1 = av.y * LOG2E, a2 = av.z * LOG2E, a3 = av.w * LOG2E;

    float ax0 = 0.f, ax1 = 0.f, ax2 = 0.f, ax3 = 0.f, ssum = 0.f;
    for (int e = rs; e < re; e += 8) {
        int e0i = e + h, e1i = e + 4 + h;
        bool l0 = e0i < re, l1 = e1i < re;
        int s0 = l0 ? srcids[e0i] : node;
        int s1 = l1 ? srcids[e1i] : node;
        const uint4 r0 = *(const uint4*)(zxb + (size_t)s0 * 64 + 4 * q);
        const uint4 r1 = *(const uint4*)(zxb + (size_t)s1 * 64 + 4 * q);

        float v0 = __uint_as_float(r0.x << 16) + zd0; v0 = v0 > 0.f ? v0 : 0.2f * v0;
        float v1 = __uint_as_float(r0.y << 16) + zd1; v1 = v1 > 0.f ? v1 : 0.2f * v1;
        float v2 = __uint_as_float(r0.z << 16) + zd2; v2 = v2 > 0.f ? v2 : 0.2f * v2;
        float v3 = __uint_as_float(r0.w << 16) + zd3; v3 = v3 > 0.f ? v3 : 0.2f * v3;
        float p0 = v0 * a0 + v1 * a1 + v2 * a2 + v3 * a3;

        float u0 = __uint_as_float(r1.x << 16) + zd0; u0 = u0 > 0.f ? u0 : 0.2f * u0;
        float u1 = __uint_as_float(r1.y << 16) + zd1; u1 = u1 > 0.f ? u1 : 0.2f * u1;
        float u2 = __uint_as_float(r1.z << 16) + zd2; u2 = u2 > 0.f ? u2 : 0.2f * u2;
        float u3 = __uint_as_float(r1.w << 16) + zd3; u3 = u3 > 0.f ? u3 : 0.2f * u3;
        float p1 = u0 * a0 + u1 * a1 + u2 * a2 + u3 * a3;

#pragma unroll
        for (int off = 8; off >= 1; off >>= 1) {
            p0 += __shfl_xor(p0, off, 64);
            p1 += __shfl_xor(p1, off, 64);
        }
        float ex0 = l0 ? __builtin_exp2f(p0) : 0.f;
        float ex1 = l1 ? __builtin_exp2f(p1) : 0.f;
        ssum += ex0 + ex1;
        ax0 += ex0 * __uint_as_float(r0.x & 0xffff0000u)
             + ex1 * __uint_as_float(r1.x & 0xffff0000u);
        ax1 += ex0 * __uint_as_float(r0.y & 0xffff0000u)
             + ex1 * __uint_as_float(r1.y & 0xffff0000u);
        ax2 += ex0 * __uint_as_float(r0.z & 0xffff0000u)
             + ex1 * __uint_as_float(r1.z & 0xffff0000u);
        ax3 += ex0 * __uint_as_float(r0.w & 0xffff0000u)
             + ex1 * __uint_as_float(r1.w & 0xffff0000u);
    }
    ssum += __shfl_xor(ssum, 16, 64); ssum += __shfl_xor(ssum, 32, 64);
    ax0  += __shfl_xor(ax0, 16, 64);  ax0  += __shfl_xor(ax0, 32, 64);
    ax1  += __shfl_xor(ax1, 16, 64);  ax1  += __shfl_xor(ax1, 32, 64);
    ax2  += __shfl_xor(ax2, 16, 64);  ax2  += __shfl_xor(ax2, 32, 64);
    ax3  += __shfl_xor(ax3, 16, 64);  ax3  += __shfl_xor(ax3, 32, 64);
    if (h == 0) {
        float inv = (re > rs) ? 1.f / ssum : 0.f;
        float4 o = make_float4(ax0 * inv, ax1 * inv, ax2 * inv, ax3 * inv);
        *(float4*)&out[(size_t)node * D + 4 * q] = o;
    }
}

extern "C" void kernel_launch(void* const* d_in, const int* in_sizes, int n_in,
                              void* d_out, int out_size, void* d_ws, size_t ws_size,
                              hipStream_t stream) {
    const float* x   = (const float*)d_in[0];
    const int*   ei  = (const int*)d_in[1];
    const float* W   = (const float*)d_in[2];
    const float* b   = (const float*)d_in[3];
    const float* att = (const float*)d_in[4];
    int n = in_sizes[0] / D;
    int e = in_sizes[1] / 2;
    const int* src = ei;
    const int* dst = ei + e;
    float* out = (float*)d_out;

    int nBlkN = (n + 255) / 256;            // scan partial blocks (must be <=512)
    int gemmBlk = (n + 63) / 64;

    // zxb[N*64 uint] | deg[N] | rowstart[N+1] | srcids[E] | slot[E] | part[512]
    unsigned int* zxb = (unsigned int*)d_ws;
    int* deg      = (int*)(zxb + (size_t)n * 64);
    int* rowstart = deg + n;
    int* srcids   = rowstart + n + 1;
    int* slot     = srcids + e;
    int* part     = slot + e;

    hipMemsetAsync(deg, 0, (size_t)n * sizeof(int), stream);
    gemm_z_count<<<gemmBlk, 256, 0, stream>>>(x, W, b, zxb, n, dst, deg, slot, e);
    scan_part<<<nBlkN, 256, 0, stream>>>(deg, part, n);
    scan_top<<<1, 512, 0, stream>>>(part, nBlkN);
    scan_final<<<nBlkN, 256, 0, stream>>>(deg, part, rowstart, n);
    csr_fill_slot<<<(e + 255) / 256, 256, 0, stream>>>(src, dst, rowstart, slot, srcids, e);
    gather4b<<<(n + 3) / 4, 256, 0, stream>>>(srcids, rowstart, zxb, att, out, n);
}

// Round 2
// 201.188 us; speedup vs baseline: 1.1595x; 1.1436x over previous
//
#include <hip/hip_runtime.h>

#define D 64
#define LOG2E 1.4426950408889634f

#define HEPT 32                 // edges per thread in hist/scatter kernels
#define HBLK (256 * HEPT)       // 8192 edges per block

using frag_ab = __attribute__((ext_vector_type(8))) short;  // 8 bf16 (4 VGPRs)
using f32x4   = __attribute__((ext_vector_type(4))) float;  // 4 fp32 acc

__device__ __forceinline__ unsigned short f2bf(float f) {      // RNE fp32->bf16
    unsigned int bits = __float_as_uint(f);
    return (unsigned short)((bits + 0x7fffu + ((bits >> 16) & 1u)) >> 16);
}

__device__ __forceinline__ frag_ab pack8(float4 a, float4 b) { // 8 fp32 -> bf16x8 frag
    frag_ab f;
    f[0] = (short)f2bf(a.x); f[1] = (short)f2bf(a.y);
    f[2] = (short)f2bf(a.z); f[3] = (short)f2bf(a.w);
    f[4] = (short)f2bf(b.x); f[5] = (short)f2bf(b.y);
    f[6] = (short)f2bf(b.z); f[7] = (short)f2bf(b.w);
    return f;
}

// Pure z = x @ W^T + b via MFMA bf16. zxb[row*64+c] = { bf16(z_c) | bf16(x_c)<<16 }.
// Per wave: 16x64 tile = 2 K-steps x 4 col-tiles = 8x mfma_f32_16x16x32_bf16.
__global__ __launch_bounds__(256) void gemm_z(const float* __restrict__ x,
                                              const float* __restrict__ W,
                                              const float* __restrict__ b,
                                              unsigned int* __restrict__ zxb,
                                              int n) {
    __shared__ float xs[64 * 68];   // stride-68 pad: conflict-free b128
    int tid = threadIdx.x;

    int row0 = blockIdx.x * 64;
    for (int i = tid; i < 64 * 16; i += 256) {
        int r = i >> 4;
        int gr = row0 + r;
        float4 v = (gr < n) ? ((const float4*)x)[(size_t)gr * 16 + (i & 15)]
                            : make_float4(0.f, 0.f, 0.f, 0.f);
        *(float4*)&xs[r * 68 + (i & 15) * 4] = v;
    }

    int l  = tid & 63;    // lane
    int w  = tid >> 6;    // wave 0..3 -> rows w*16..w*16+15
    int lr = l & 15;      // A-row / B-col / D-col within 16-tile
    int hi = l >> 4;      // 0..3
    int lk = hi * 8;      // k offset within K=32 chunk

    // B frags straight from W (16 KB, L1-resident; B^T == W so k-elems contiguous)
    frag_ab bfr[4][2];
#pragma unroll
    for (int colt = 0; colt < 4; ++colt) {
#pragma unroll
        for (int ks = 0; ks < 2; ++ks) {
            const float* wp = W + (colt * 16 + lr) * 64 + ks * 32 + lk;
            bfr[colt][ks] = pack8(*(const float4*)wp, *(const float4*)(wp + 4));
        }
    }

    __syncthreads();

    frag_ab afr[2];
#pragma unroll
    for (int ks = 0; ks < 2; ++ks) {
        const float* ap = &xs[(w * 16 + lr) * 68 + ks * 32 + lk];
        afr[ks] = pack8(*(const float4*)ap, *(const float4*)(ap + 4));
    }

    f32x4 zero = {0.f, 0.f, 0.f, 0.f};
    f32x4 acc[4] = {zero, zero, zero, zero};
#pragma unroll
    for (int ks = 0; ks < 2; ++ks) {
#pragma unroll
        for (int colt = 0; colt < 4; ++colt) {
            acc[colt] = __builtin_amdgcn_mfma_f32_16x16x32_bf16(
                afr[ks], bfr[colt][ks], acc[colt], 0, 0, 0);
        }
    }

    // D mapping: col=lane&15, row=(lane>>4)*4+reg (m89-verified)
#pragma unroll
    for (int colt = 0; colt < 4; ++colt) {
        int col = colt * 16 + lr;
        float bb = b[col];
#pragma unroll
        for (int r = 0; r < 4; ++r) {
            int lrow = w * 16 + hi * 4 + r;
            int row  = row0 + lrow;
            if (row < n) {
                float z  = acc[colt][r] + bb;
                float xv = xs[lrow * 68 + col];
                unsigned int u = (unsigned int)f2bf(z) |
                                 ((unsigned int)f2bf(xv) << 16);
                zxb[(size_t)row * 64 + col] = u;   // 64B-segment coalesced
            }
        }
    }
}

// ---- MSD counting sort, level 1: 256-node buckets (dst>>8), NO global atomics ----
__global__ __launch_bounds__(256) void msd_hist(const int* __restrict__ dst,
                                                int* __restrict__ hist,
                                                int e_cnt, int nbuck, int nblk) {
    __shared__ int cnt[512];
    int t = threadIdx.x;
    for (int i = t; i < nbuck; i += 256) cnt[i] = 0;
    __syncthreads();
    int base = blockIdx.x * HBLK;
    for (int j = 0; j < HEPT; ++j) {
        int e = base + j * 256 + t;
        if (e < e_cnt) atomicAdd(&cnt[dst[e] >> 8], 1);   // LDS atomic
    }
    __syncthreads();
    for (int i = t; i < nbuck; i += 256)
        hist[(size_t)i * nblk + blockIdx.x] = cnt[i];     // bin-major for scan
}

// ---- 3-phase coalesced scan (over the bin-major histogram) ----
__global__ __launch_bounds__(256) void scan_part(const int* __restrict__ deg,
                                                 int* __restrict__ part, int n) {
    __shared__ int red[256];
    int t = threadIdx.x;
    int i = blockIdx.x * 256 + t;
    red[t] = (i < n) ? deg[i] : 0;
    __syncthreads();
    for (int off = 128; off >= 1; off >>= 1) {
        if (t < off) red[t] += red[t + off];
        __syncthreads();
    }
    if (t == 0) part[blockIdx.x] = red[0];
}

__global__ __launch_bounds__(512) void scan_top(int* __restrict__ part, int B) {
    __shared__ int s[512];
    int t = threadIdx.x;
    int v = (t < B) ? part[t] : 0;
    s[t] = v;
    __syncthreads();
    for (int off = 1; off < 512; off <<= 1) {
        int u = (t >= off) ? s[t - off] : 0;
        __syncthreads();
        s[t] += u;
        __syncthreads();
    }
    if (t < B) part[t] = s[t] - v;   // exclusive
}

// in-place exclusive scan finalize (data aliases input; each index touched by one
// thread, read-before-write). Writes total at data[n] as sentinel.
__global__ __launch_bounds__(256) void scan_final_ip(int* data,
                                                     const int* __restrict__ part, int n) {
    __shared__ int s[256];
    int t = threadIdx.x;
    int i = blockIdx.x * 256 + t;
    int v = (i < n) ? data[i] : 0;
    s[t] = v;
    __syncthreads();
    for (int off = 1; off < 256; off <<= 1) {
        int u = (t >= off) ? s[t - off] : 0;
        __syncthreads();
        s[t] += u;
        __syncthreads();
    }
    int incl = s[t] + part[blockIdx.x];
    if (i < n) data[i] = incl - v;
    if (i == n - 1) data[n] = incl;
}

// partition edges into buckets: packed[pos] = src | (dst&255)<<24.
// Per-block LDS cursors start at scanned base(bin,blk) -> disjoint output ranges,
// writes are ~21-int sequential runs per (blk,bin) -> L2 write-combines.
__global__ __launch_bounds__(256) void msd_scatter(const int* __restrict__ src,
                                                   const int* __restrict__ dst,
                                                   const int* __restrict__ histS,
                                                   unsigned int* __restrict__ packed,
                                                   int e_cnt, int nbuck, int nblk) {
    __shared__ int cur[512];
    int t = threadIdx.x;
    int blk = blockIdx.x;
    for (int i = t; i < nbuck; i += 256) cur[i] = histS[(size_t)i * nblk + blk];
    __syncthreads();
    int base = blk * HBLK;
    for (int j = 0; j < HEPT; ++j) {
        int e = base + j * 256 + t;
        if (e < e_cnt) {
            int d = dst[e];
            int s = src[e];
            int pos = atomicAdd(&cur[d >> 8], 1);          // LDS atomic, returns old
            packed[pos] = (unsigned int)s | ((unsigned int)(d & 255) << 24);
        }
    }
}

// level 2: one block per 256-node bucket (~3072 edges avg). LDS count + scan ->
// rowstart written directly; srcids scattered within the bucket's contiguous region.
__global__ __launch_bounds__(256) void bucket_csr(const unsigned int* __restrict__ packed,
                                                  const int* __restrict__ histS,
                                                  int* __restrict__ rowstart,
                                                  int* __restrict__ srcids,
                                                  int n, int e_cnt, int nblk) {
    __shared__ int cnt[256];
    __shared__ int s[256];
    __shared__ int cur[256];
    int t = threadIdx.x;
    int b = blockIdx.x;
    int base = histS[(size_t)b * nblk];
    int end  = histS[(size_t)(b + 1) * nblk];   // b==last: hits sentinel == e_cnt
    int m = end - base;

    cnt[t] = 0;
    __syncthreads();
    for (int i = t; i < m; i += 256)
        atomicAdd(&cnt[packed[base + i] >> 24], 1);
    __syncthreads();
    s[t] = cnt[t];
    __syncthreads();
    for (int off = 1; off < 256; off <<= 1) {
        int u = (t >= off) ? s[t - off] : 0;
        __syncthreads();
        s[t] += u;
        __syncthreads();
    }
    int excl = s[t] - cnt[t];
    cur[t] = base + excl;
    int node = (b << 8) + t;
    if (node < n) rowstart[node] = base + excl;
    if (b == gridDim.x - 1 && t == 0) rowstart[n] = e_cnt;
    __syncthreads();
    for (int i = t; i < m; i += 256) {
        unsigned int p = packed[base + i];
        int pos = atomicAdd(&cur[p >> 24], 1);             // LDS atomic
        srcids[pos] = (int)(p & 0xFFFFFFu);
    }
}

// wave-per-node, quarter-wave per edge, 8 edges/iter (2x unroll).
// bf16-packed row: zxb[row*64 + d] = { bf16 z_d | bf16 x_d << 16 }, 256 B/row.
__global__ __launch_bounds__(256) void gather4b(const int* __restrict__ srcids,
                                                const int* __restrict__ rowstart,
                                                const unsigned int* __restrict__ zxb,
                                                const float* __restrict__ att,
                                                float* __restrict__ out, int n) {
    int lane = threadIdx.x & 63;
    int node = blockIdx.x * 4 + (threadIdx.x >> 6);
    if (node >= n) return;
    int q = lane & 15;                 // dim group: 4q..4q+3
    int h = lane >> 4;                 // edge slot 0..3
    int rs = rowstart[node], re = rowstart[node + 1];

    const uint4 zdv = *(const uint4*)(zxb + (size_t)node * 64 + 4 * q);
    float zd0 = __uint_as_float(zdv.x << 16);
    float zd1 = __uint_as_float(zdv.y << 16);
    float zd2 = __uint_as_float(zdv.z << 16);
    float zd3 = __uint_as_float(zdv.w << 16);
    float4 av = *(const float4*)(att + 4 * q);
    float a0 = av.x * LOG2E, a1 = av.y * LOG2E, a2 = av.z * LOG2E, a3 = av.w * LOG2E;

    float ax0 = 0.f, ax1 = 0.f, ax2 = 0.f, ax3 = 0.f, ssum = 0.f;
    for (int e = rs; e < re; e += 8) {
        int e0i = e + h, e1i = e + 4 + h;
        bool l0 = e0i < re, l1 = e1i < re;
        int s0 = l0 ? srcids[e0i] : node;
        int s1 = l1 ? srcids[e1i] : node;
        const uint4 r0 = *(const uint4*)(zxb + (size_t)s0 * 64 + 4 * q);
        const uint4 r1 = *(const uint4*)(zxb + (size_t)s1 * 64 + 4 * q);

        float v0 = __uint_as_float(r0.x << 16) + zd0; v0 = v0 > 0.f ? v0 : 0.2f * v0;
        float v1 = __uint_as_float(r0.y << 16) + zd1; v1 = v1 > 0.f ? v1 : 0.2f * v1;
        float v2 = __uint_as_float(r0.z << 16) + zd2; v2 = v2 > 0.f ? v2 : 0.2f * v2;
        float v3 = __uint_as_float(r0.w << 16) + zd3; v3 = v3 > 0.f ? v3 : 0.2f * v3;
        float p0 = v0 * a0 + v1 * a1 + v2 * a2 + v3 * a3;

        float u0 = __uint_as_float(r1.x << 16) + zd0; u0 = u0 > 0.f ? u0 : 0.2f * u0;
        float u1 = __uint_as_float(r1.y << 16) + zd1; u1 = u1 > 0.f ? u1 : 0.2f * u1;
        float u2 = __uint_as_float(r1.z << 16) + zd2; u2 = u2 > 0.f ? u2 : 0.2f * u2;
        float u3 = __uint_as_float(r1.w << 16) + zd3; u3 = u3 > 0.f ? u3 : 0.2f * u3;
        float p1 = u0 * a0 + u1 * a1 + u2 * a2 + u3 * a3;

#pragma unroll
        for (int off = 8; off >= 1; off >>= 1) {
            p0 += __shfl_xor(p0, off, 64);
            p1 += __shfl_xor(p1, off, 64);
        }
        float ex0 = l0 ? __builtin_exp2f(p0) : 0.f;
        float ex1 = l1 ? __builtin_exp2f(p1) : 0.f;
        ssum += ex0 + ex1;
        ax0 += ex0 * __uint_as_float(r0.x & 0xffff0000u)
             + ex1 * __uint_as_float(r1.x & 0xffff0000u);
        ax1 += ex0 * __uint_as_float(r0.y & 0xffff0000u)
             + ex1 * __uint_as_float(r1.y & 0xffff0000u);
        ax2 += ex0 * __uint_as_float(r0.z & 0xffff0000u)
             + ex1 * __uint_as_float(r1.z & 0xffff0000u);
        ax3 += ex0 * __uint_as_float(r0.w & 0xffff0000u)
             + ex1 * __uint_as_float(r1.w & 0xffff0000u);
    }
    ssum += __shfl_xor(ssum, 16, 64); ssum += __shfl_xor(ssum, 32, 64);
    ax0  += __shfl_xor(ax0, 16, 64);  ax0  += __shfl_xor(ax0, 32, 64);
    ax1  += __shfl_xor(ax1, 16, 64);  ax1  += __shfl_xor(ax1, 32, 64);
    ax2  += __shfl_xor(ax2, 16, 64);  ax2  += __shfl_xor(ax2, 32, 64);
    ax3  += __shfl_xor(ax3, 16, 64);  ax3  += __shfl_xor(ax3, 32, 64);
    if (h == 0) {
        float inv = (re > rs) ? 1.f / ssum : 0.f;
        float4 o = make_float4(ax0 * inv, ax1 * inv, ax2 * inv, ax3 * inv);
        *(float4*)&out[(size_t)node * D + 4 * q] = o;
    }
}

extern "C" void kernel_launch(void* const* d_in, const int* in_sizes, int n_in,
                              void* d_out, int out_size, void* d_ws, size_t ws_size,
                              hipStream_t stream) {
    const float* x   = (const float*)d_in[0];
    const int*   ei  = (const int*)d_in[1];
    const float* W   = (const float*)d_in[2];
    const float* b   = (const float*)d_in[3];
    const float* att = (const float*)d_in[4];
    int n = in_sizes[0] / D;
    int e = in_sizes[1] / 2;
    const int* src = ei;
    const int* dst = ei + e;
    float* out = (float*)d_out;

    int gemmBlk = (n + 63) / 64;
    int nbuck = (n + 255) >> 8;                  // 391 buckets of 256 nodes
    int nblk1 = (e + HBLK - 1) / HBLK;           // 147 edge blocks
    int NBH   = nbuck * nblk1;                   // 57477 histogram cells (<= n)
    int scanBlk = (NBH + 255) / 256;             // 225 (<= 512 for scan_top)

    // ws: zxb[n*64 uint] | hist[NBH+1] (fits old deg[n] slot) | rowstart[n+1]
    //     | srcids[e] | packed[e] (old slot[e] spot) | part[512]
    unsigned int* zxb = (unsigned int*)d_ws;
    int* hist     = (int*)(zxb + (size_t)n * 64);
    int* rowstart = hist + n;                    // NBH+1 <= n guaranteed here
    int* srcids   = rowstart + n + 1;
    unsigned int* packed = (unsigned int*)(srcids + e);
    int* part     = (int*)(packed + e);

    gemm_z<<<gemmBlk, 256, 0, stream>>>(x, W, b, zxb, n);
    msd_hist<<<nblk1, 256, 0, stream>>>(dst, hist, e, nbuck, nblk1);
    scan_part<<<scanBlk, 256, 0, stream>>>(hist, part, NBH);
    scan_top<<<1, 512, 0, stream>>>(part, scanBlk);
    scan_final_ip<<<scanBlk, 256, 0, stream>>>(hist, part, NBH);
    msd_scatter<<<nblk1, 256, 0, stream>>>(src, dst, hist, packed, e, nbuck, nblk1);
    bucket_csr<<<nbuck, 256, 0, stream>>>(packed, hist, rowstart, srcids, n, e, nblk1);
    gather4b<<<(n + 3) / 4, 256, 0, stream>>>(srcids, rowstart, zxb, att, out, n);
}